// Round 2
// baseline (3378.568 us; speedup 1.0000x reference)
//
#include <hip/hip_runtime.h>
#include <math.h>

#define BB 4
#define TT 4096
#define DD 768
#define SS 1024
#define S2 2048
#define KTOP 8
#define NC 16
#define RWEIGHT 0.1f

// ---------------------------------------------------------------------------
// build_slots: one batch. slots[0:S] = window-mean(4) of x, slots[S:2S] = pm.
// ---------------------------------------------------------------------------
__global__ __launch_bounds__(256) void build_slots(
    const float* __restrict__ x,    // [T][D] batch base
    const float* __restrict__ pm,   // [S][D]
    float* __restrict__ slots)      // [2S][D] batch base
{
    int i = blockIdx.x * 256 + threadIdx.x;      // over S*D = 786432 (grid exact)
    int s = i / DD;
    int d = i - s * DD;
    const float* xb = x + (long)(4 * s) * DD + d;
    float pooled = 0.25f * (xb[0] + xb[DD] + xb[2 * DD] + xb[3 * DD]);
    slots[i] = pooled;
    slots[(long)SS * DD + i] = pm[i];
}

// ---------------------------------------------------------------------------
// f64 GEMM: C64[M,N] = f64( A32[M,K] @ B32[K,N] ) + bias32[N]
// 64x64 tile, BK=16, 256 threads, 4x4 f64 microtile. Selection-critical path.
// ---------------------------------------------------------------------------
__global__ __launch_bounds__(256) void gemm_f64(
    const float* __restrict__ A, const float* __restrict__ B,
    const float* __restrict__ bias, double* __restrict__ C,
    int M, int N, int K)
{
    __shared__ double As[16][66];
    __shared__ double Bs[16][66];
    const int tid = threadIdx.x;
    const int tx = tid & 15;
    const int ty = tid >> 4;
    const long bm = (long)blockIdx.y * 64;
    const long bn = (long)blockIdx.x * 64;

    double acc[4][4];
#pragma unroll
    for (int i = 0; i < 4; ++i)
#pragma unroll
        for (int j = 0; j < 4; ++j) acc[i][j] = 0.0;

    const int arow = tid >> 2, acol = (tid & 3) * 4;     // A tile 64x16
    const int brow = tid >> 4, bcol = (tid & 15) * 4;    // B tile 16x64

    for (int k0 = 0; k0 < K; k0 += 16) {
        float4 av = *(const float4*)&A[(bm + arow) * (long)K + k0 + acol];
        float4 bv = *(const float4*)&B[(long)(k0 + brow) * N + bn + bcol];
        __syncthreads();
        As[acol + 0][arow] = (double)av.x; As[acol + 1][arow] = (double)av.y;
        As[acol + 2][arow] = (double)av.z; As[acol + 3][arow] = (double)av.w;
        Bs[brow][bcol + 0] = (double)bv.x; Bs[brow][bcol + 1] = (double)bv.y;
        Bs[brow][bcol + 2] = (double)bv.z; Bs[brow][bcol + 3] = (double)bv.w;
        __syncthreads();
#pragma unroll
        for (int kk = 0; kk < 16; ++kk) {
            double a[4], b[4];
#pragma unroll
            for (int i = 0; i < 4; ++i) a[i] = As[kk][ty * 4 + i];
#pragma unroll
            for (int j = 0; j < 4; ++j) b[j] = Bs[kk][tx * 4 + j];
#pragma unroll
            for (int i = 0; i < 4; ++i)
#pragma unroll
                for (int j = 0; j < 4; ++j) acc[i][j] = fma(a[i], b[j], acc[i][j]);
        }
    }
#pragma unroll
    for (int i = 0; i < 4; ++i) {
        long row = bm + ty * 4 + i;
#pragma unroll
        for (int j = 0; j < 4; ++j) {
            long col = bn + tx * 4 + j;
            C[row * N + col] = acc[i][j] + (double)bias[col];
        }
    }
}

// ---------------------------------------------------------------------------
// f32 tiled GEMM (NN): C = alpha*A@B + bscale*bias.  (v and proj path)
// 128x128 tile, BK=16, 256 threads, 8x8 microtile as 2x2 of 4x4.
// ---------------------------------------------------------------------------
__global__ __launch_bounds__(256) void gemm_f32nn(
    const float* __restrict__ A, const float* __restrict__ Bm,
    float* __restrict__ C, const float* __restrict__ bias,
    int M, int N, int K, float alpha, float bscale)
{
    __shared__ float As[16][132];
    __shared__ float Bs[16][132];
    const int tid = threadIdx.x;
    const int tx = tid & 15;
    const int ty = tid >> 4;
    const long bm = (long)blockIdx.y * 128;
    const long bn = (long)blockIdx.x * 128;

    float acc[2][2][4][4];
#pragma unroll
    for (int a = 0; a < 2; ++a)
#pragma unroll
        for (int b = 0; b < 2; ++b)
#pragma unroll
            for (int i = 0; i < 4; ++i)
#pragma unroll
                for (int j = 0; j < 4; ++j) acc[a][b][i][j] = 0.f;

    const int lrow = tid >> 2;            // 0..63
    const int lcol = (tid & 3) * 4;       // 0,4,8,12
    const int brow = tid >> 5;            // 0..7
    const int bcol = (tid & 31) * 4;      // 0..124

    for (int k0 = 0; k0 < K; k0 += 16) {
        float4 av0 = *(const float4*)&A[(bm + lrow) * (long)K + k0 + lcol];
        float4 av1 = *(const float4*)&A[(bm + lrow + 64) * (long)K + k0 + lcol];
        float4 bv0 = *(const float4*)&Bm[(long)(k0 + brow) * N + bn + bcol];
        float4 bv1 = *(const float4*)&Bm[(long)(k0 + brow + 8) * N + bn + bcol];
        __syncthreads();
        As[lcol + 0][lrow] = av0.x; As[lcol + 1][lrow] = av0.y;
        As[lcol + 2][lrow] = av0.z; As[lcol + 3][lrow] = av0.w;
        As[lcol + 0][lrow + 64] = av1.x; As[lcol + 1][lrow + 64] = av1.y;
        As[lcol + 2][lrow + 64] = av1.z; As[lcol + 3][lrow + 64] = av1.w;
        *(float4*)&Bs[brow][bcol] = bv0;
        *(float4*)&Bs[brow + 8][bcol] = bv1;
        __syncthreads();
#pragma unroll
        for (int kk = 0; kk < 16; ++kk) {
            float a0[4], a1[4], b0[4], b1[4];
            *(float4*)a0 = *(const float4*)&As[kk][ty * 4];
            *(float4*)a1 = *(const float4*)&As[kk][64 + ty * 4];
            *(float4*)b0 = *(const float4*)&Bs[kk][tx * 4];
            *(float4*)b1 = *(const float4*)&Bs[kk][64 + tx * 4];
#pragma unroll
            for (int i = 0; i < 4; ++i)
#pragma unroll
                for (int j = 0; j < 4; ++j) {
                    acc[0][0][i][j] = fmaf(a0[i], b0[j], acc[0][0][i][j]);
                    acc[0][1][i][j] = fmaf(a0[i], b1[j], acc[0][1][i][j]);
                    acc[1][0][i][j] = fmaf(a1[i], b0[j], acc[1][0][i][j]);
                    acc[1][1][i][j] = fmaf(a1[i], b1[j], acc[1][1][i][j]);
                }
        }
    }
#pragma unroll
    for (int mi = 0; mi < 2; ++mi)
#pragma unroll
        for (int i = 0; i < 4; ++i) {
            long row = bm + mi * 64 + ty * 4 + i;
#pragma unroll
            for (int ni = 0; ni < 2; ++ni) {
                long col = bn + ni * 64 + tx * 4;
                float4 o;
                o.x = alpha * acc[mi][ni][i][0] + bscale * bias[col + 0];
                o.y = alpha * acc[mi][ni][i][1] + bscale * bias[col + 1];
                o.z = alpha * acc[mi][ni][i][2] + bscale * bias[col + 2];
                o.w = alpha * acc[mi][ni][i][3] + bscale * bias[col + 3];
                *(float4*)&C[row * (long)N + col] = o;
            }
        }
}

// ---------------------------------------------------------------------------
// scores (f32) = alpha * q64[M,K] @ k64[N,K]^T  — candidate preselection only.
// Inputs are f64, cast to f32 at LDS staging. 128x128 tile as gemm_f32nn.
// ---------------------------------------------------------------------------
__global__ __launch_bounds__(256) void gemm_nt_scores(
    const double* __restrict__ A64, const double* __restrict__ B64,
    float* __restrict__ C, int M, int N, int K, float alpha)
{
    __shared__ float As[16][132];
    __shared__ float Bs[16][132];
    const int tid = threadIdx.x;
    const int tx = tid & 15;
    const int ty = tid >> 4;
    const long bm = (long)blockIdx.y * 128;
    const long bn = (long)blockIdx.x * 128;

    float acc[2][2][4][4];
#pragma unroll
    for (int a = 0; a < 2; ++a)
#pragma unroll
        for (int b = 0; b < 2; ++b)
#pragma unroll
            for (int i = 0; i < 4; ++i)
#pragma unroll
                for (int j = 0; j < 4; ++j) acc[a][b][i][j] = 0.f;

    const int lrow = tid >> 2;            // 0..63
    const int lcol = (tid & 3) * 4;       // 0,4,8,12

    for (int k0 = 0; k0 < K; k0 += 16) {
        const double2* ap0 = (const double2*)&A64[(bm + lrow) * (long)K + k0 + lcol];
        const double2* ap1 = (const double2*)&A64[(bm + lrow + 64) * (long)K + k0 + lcol];
        const double2* bp0 = (const double2*)&B64[(bn + lrow) * (long)K + k0 + lcol];
        const double2* bp1 = (const double2*)&B64[(bn + lrow + 64) * (long)K + k0 + lcol];
        double2 a00 = ap0[0], a01 = ap0[1], a10 = ap1[0], a11 = ap1[1];
        double2 b00 = bp0[0], b01 = bp0[1], b10 = bp1[0], b11 = bp1[1];
        __syncthreads();
        As[lcol + 0][lrow] = (float)a00.x; As[lcol + 1][lrow] = (float)a00.y;
        As[lcol + 2][lrow] = (float)a01.x; As[lcol + 3][lrow] = (float)a01.y;
        As[lcol + 0][lrow + 64] = (float)a10.x; As[lcol + 1][lrow + 64] = (float)a10.y;
        As[lcol + 2][lrow + 64] = (float)a11.x; As[lcol + 3][lrow + 64] = (float)a11.y;
        Bs[lcol + 0][lrow] = (float)b00.x; Bs[lcol + 1][lrow] = (float)b00.y;
        Bs[lcol + 2][lrow] = (float)b01.x; Bs[lcol + 3][lrow] = (float)b01.y;
        Bs[lcol + 0][lrow + 64] = (float)b10.x; Bs[lcol + 1][lrow + 64] = (float)b10.y;
        Bs[lcol + 2][lrow + 64] = (float)b11.x; Bs[lcol + 3][lrow + 64] = (float)b11.y;
        __syncthreads();
#pragma unroll
        for (int kk = 0; kk < 16; ++kk) {
            float a0[4], a1[4], b0[4], b1[4];
            *(float4*)a0 = *(const float4*)&As[kk][ty * 4];
            *(float4*)a1 = *(const float4*)&As[kk][64 + ty * 4];
            *(float4*)b0 = *(const float4*)&Bs[kk][tx * 4];
            *(float4*)b1 = *(const float4*)&Bs[kk][64 + tx * 4];
#pragma unroll
            for (int i = 0; i < 4; ++i)
#pragma unroll
                for (int j = 0; j < 4; ++j) {
                    acc[0][0][i][j] = fmaf(a0[i], b0[j], acc[0][0][i][j]);
                    acc[0][1][i][j] = fmaf(a0[i], b1[j], acc[0][1][i][j]);
                    acc[1][0][i][j] = fmaf(a1[i], b0[j], acc[1][0][i][j]);
                    acc[1][1][i][j] = fmaf(a1[i], b1[j], acc[1][1][i][j]);
                }
        }
    }
#pragma unroll
    for (int mi = 0; mi < 2; ++mi)
#pragma unroll
        for (int i = 0; i < 4; ++i) {
            long row = bm + mi * 64 + ty * 4 + i;
#pragma unroll
            for (int ni = 0; ni < 2; ++ni) {
                long col = bn + ni * 64 + tx * 4;
                float4 o;
                o.x = alpha * acc[mi][ni][i][0];
                o.y = alpha * acc[mi][ni][i][1];
                o.z = alpha * acc[mi][ni][i][2];
                o.w = alpha * acc[mi][ni][i][3];
                *(float4*)&C[row * (long)N + col] = o;
            }
        }
}

// ---------------------------------------------------------------------------
// One wave per row: top-NC candidates by f32 scores -> f64 rescore with
// q64/k64 -> f64 top-8 (desc val, asc idx = jax.lax.top_k) -> f64 softmax
// -> weighted gather of v (f32).
// ---------------------------------------------------------------------------
__global__ __launch_bounds__(256) void topk_rescore_combine(
    const float* __restrict__ scores,   // [rows][2048] chunk base
    const double* __restrict__ q64,     // [rows][768] chunk base
    const double* __restrict__ k64,     // [2048][768]
    const float* __restrict__ v,        // [2048][768]
    float* __restrict__ retr)           // [rows][768] chunk base
{
    const int lane = threadIdx.x & 63;
    const int wave = threadIdx.x >> 6;
    const int row = blockIdx.x * 4 + wave;

    // --- 1) candidate preselection: top-NC indices by f32 score ---
    const float* srow = scores + (long)row * S2;
    float vals[32];
#pragma unroll
    for (int i = 0; i < 32; ++i) vals[i] = srow[lane + (i << 6)];

    int cand[NC];
#pragma unroll
    for (int r = 0; r < NC; ++r) {
        float bvv = -3.4e38f; int bii = 0x7fffffff;
#pragma unroll
        for (int i = 0; i < 32; ++i)
            if (vals[i] > bvv) { bvv = vals[i]; bii = lane + (i << 6); }
#pragma unroll
        for (int off = 32; off > 0; off >>= 1) {
            float ov = __shfl_xor(bvv, off);
            int   oi = __shfl_xor(bii, off);
            if (ov > bvv || (ov == bvv && oi < bii)) { bvv = ov; bii = oi; }
        }
        cand[r] = bii;
        if ((bii & 63) == lane) vals[bii >> 6] = -3.4e38f;
    }

    // --- 2) f64 rescore of candidates ---
    const double SQD = sqrt((double)DD);
    double qr[12];
    const double* qrow = q64 + (long)row * DD;
#pragma unroll
    for (int i = 0; i < 12; ++i) qr[i] = qrow[lane + (i << 6)];

    double cs[NC];
#pragma unroll
    for (int c = 0; c < NC; ++c) {
        const double* kr = k64 + (long)cand[c] * DD;
        double p = 0.0;
#pragma unroll
        for (int i = 0; i < 12; ++i) p = fma(qr[i], kr[lane + (i << 6)], p);
#pragma unroll
        for (int off = 32; off > 0; off >>= 1) p += __shfl_xor(p, off);
        cs[c] = p / SQD;
    }

    // --- 3) f64 top-8, desc value, asc slot index ---
    int sel[KTOP]; double sv[KTOP];
    unsigned used = 0;
#pragma unroll
    for (int r = 0; r < KTOP; ++r) {
        int bi = -1; double best = 0.0;
#pragma unroll
        for (int c = 0; c < NC; ++c) {
            if (used & (1u << c)) continue;
            if (bi < 0 || cs[c] > best || (cs[c] == best && cand[c] < cand[bi])) {
                best = cs[c]; bi = c;
            }
        }
        sel[r] = bi; sv[r] = best; used |= (1u << bi);
    }

    // --- 4) f64 softmax over top-8 ---
    double m = sv[0];
    double es[KTOP], ssum = 0.0;
#pragma unroll
    for (int r = 0; r < KTOP; ++r) { es[r] = exp(sv[r] - m); ssum += es[r]; }
    float w[KTOP];
#pragma unroll
    for (int r = 0; r < KTOP; ++r) w[r] = (float)(es[r] / ssum);

    // --- 5) weighted combine of v rows ---
    const float4* v4 = (const float4*)v;
    float4* o4 = (float4*)(retr + (long)row * DD);
#pragma unroll
    for (int c3 = 0; c3 < 3; ++c3) {               // D/4 = 192 = 3*64
        int col = c3 * 64 + lane;
        float4 accv = {0.f, 0.f, 0.f, 0.f};
#pragma unroll
        for (int r = 0; r < KTOP; ++r) {
            float4 vv = v4[(long)cand[sel[r]] * (DD / 4) + col];
            accv.x += w[r] * vv.x; accv.y += w[r] * vv.y;
            accv.z += w[r] * vv.z; accv.w += w[r] * vv.w;
        }
        o4[col] = accv;
    }
}

// ---------------------------------------------------------------------------
extern "C" void kernel_launch(void* const* d_in, const int* in_sizes, int n_in,
                              void* d_out, int out_size, void* d_ws, size_t ws_size,
                              hipStream_t stream)
{
    const float* x  = (const float*)d_in[0];
    const float* Wq = (const float*)d_in[1];
    const float* bq = (const float*)d_in[2];
    const float* Wk = (const float*)d_in[3];
    const float* bk = (const float*)d_in[4];
    const float* Wv = (const float*)d_in[5];
    const float* bv = (const float*)d_in[6];
    const float* Wp = (const float*)d_in[7];
    const float* bp = (const float*)d_in[8];
    const float* pm = (const float*)d_in[9];
    float* out = (float*)d_out;
    float* ws  = (float*)d_ws;

    const float inv_sqrt_d = 1.0f / sqrtf((float)DD);
    const long TD  = (long)TT * DD;        // 3,145,728
    const long SD2 = (long)S2 * DD;        // 1,572,864

    // workspace need (bytes) for chunk size tc:
    //   slots32[S2*D] + k64[S2*D (f64=2 f32u)] + v32[S2*D]
    //   + q64c[tc*768*2] + scores[tc*2048] + retr[tc*768]
    auto need = [&](long tc) -> size_t {
        return (size_t)4 * (size_t)(4 * SD2 + tc * (1536 + 2048 + 768));
    };
    long tc;
    if      (ws_size >= need(4096)) tc = 4096;
    else if (ws_size >= need(2048)) tc = 2048;
    else if (ws_size >= need(1024)) tc = 1024;
    else                            tc = 512;

    float*  slots32 = ws;
    double* k64     = (double*)(ws + SD2);
    float*  v32     = ws + 3 * SD2;
    float*  base    = ws + 4 * SD2;
    double* q64c    = (double*)base;
    float*  scoresc = base + tc * 1536;
    float*  retrc   = scoresc + tc * 2048;

    for (int b = 0; b < BB; ++b) {
        const float* xb = x + (long)b * TD;
        build_slots<<<(SS * DD) / 256, 256, 0, stream>>>(xb, pm, slots32);
        gemm_f64<<<dim3(DD / 64, S2 / 64), 256, 0, stream>>>(
            slots32, Wk, bk, k64, S2, DD, DD);
        gemm_f32nn<<<dim3(DD / 128, S2 / 128), 256, 0, stream>>>(
            slots32, Wv, v32, bv, S2, DD, DD, 1.f, 1.f);

        for (long t0 = 0; t0 < TT; t0 += tc) {
            gemm_f64<<<dim3(DD / 64, tc / 64), 256, 0, stream>>>(
                xb + t0 * DD, Wq, bq, q64c, (int)tc, DD, DD);
            gemm_nt_scores<<<dim3(S2 / 128, tc / 128), 256, 0, stream>>>(
                q64c, k64, scoresc, (int)tc, S2, DD, inv_sqrt_d);
            topk_rescore_combine<<<tc / 4, 256, 0, stream>>>(
                scoresc, q64c, k64, v32, retrc);
            gemm_f32nn<<<dim3(DD / 128, tc / 128), 256, 0, stream>>>(
                retrc, Wp, out + ((long)b * TT + t0) * DD, bp,
                (int)tc, DD, DD, RWEIGHT, RWEIGHT);
        }
    }
}

// Round 3
// 1839.184 us; speedup vs baseline: 1.8370x; 1.8370x over previous
//
#include <hip/hip_runtime.h>
#include <math.h>

#define BB 4
#define TT 4096
#define DD 768
#define SS 1024
#define S2 2048
#define KTOP 8
#define RWEIGHT 0.1f
#define TAU 2e-4f
#define AMB_CAP 1024

typedef __attribute__((ext_vector_type(8))) _Float16 f16x8;
typedef __attribute__((ext_vector_type(4))) float f32x4;
typedef _Float16 f16;

// ---------------------------------------------------------------------------
// build_slots: slots[0:S] = window-mean(4) of x (f32), slots[S:2S] = pm.
// ---------------------------------------------------------------------------
__global__ __launch_bounds__(256) void build_slots(
    const float* __restrict__ x, const float* __restrict__ pm,
    float* __restrict__ slots)
{
    int i = blockIdx.x * 256 + threadIdx.x;      // over S*D = 786432
    int s = i / DD;
    int d = i - s * DD;
    const float* xb = x + (size_t)(4 * s) * DD + d;
    slots[i] = 0.25f * (xb[0] + xb[DD] + xb[2 * DD] + xb[3 * DD]);
    slots[(size_t)SS * DD + i] = pm[i];
}

// ---------------------------------------------------------------------------
// transpose768: WT[j][i] = W[i][j], 768x768 f32.
// ---------------------------------------------------------------------------
__global__ __launch_bounds__(256) void transpose768(
    const float* __restrict__ W, float* __restrict__ WT)
{
    __shared__ float t[32][33];
    int bx = blockIdx.x * 32, by = blockIdx.y * 32;
    int lx = threadIdx.x & 31, ly = threadIdx.x >> 5;   // 32 x 8
#pragma unroll
    for (int r = 0; r < 32; r += 8)
        t[ly + r][lx] = W[(size_t)(bx + ly + r) * 768 + by + lx];
    __syncthreads();
#pragma unroll
    for (int r = 0; r < 32; r += 8)
        WT[(size_t)(by + ly + r) * 768 + bx + lx] = t[lx][ly + r];
}

__global__ void zero1(int* p) { *p = 0; }

// ---------------------------------------------------------------------------
// f16-split MFMA NT GEMM:  C[M,N] = alpha * A[M,768] @ B[N,768]^T + bscale*bias
// Split a = h + m (f16 each); products hh + hm + mh (mm ~2^-24 dropped).
// 128x128 tile, BK=32, 256 thr (4 waves 2x2, 64x64 each), 16x16x32 f16 MFMA.
// M, N multiples of 128. K fixed 768.
// ---------------------------------------------------------------------------
__global__ __launch_bounds__(256) void mfma_nt_split(
    const float* __restrict__ A, const float* __restrict__ B,
    const float* __restrict__ bias, float* __restrict__ C,
    int N, float alpha, float bscale)
{
    __shared__ f16 Ah[128 * 32], Am[128 * 32], Bh[128 * 32], Bm[128 * 32];
    const int tid = threadIdx.x;
    const int lane = tid & 63;
    const int wc = (tid >> 6) & 1;
    const int wr = (tid >> 7) & 1;
    const size_t bm = (size_t)blockIdx.y * 128;
    const size_t bn = (size_t)blockIdx.x * 128;

    f32x4 acc[4][4];
#pragma unroll
    for (int i = 0; i < 4; ++i)
#pragma unroll
        for (int j = 0; j < 4; ++j) acc[i][j] = (f32x4){0.f, 0.f, 0.f, 0.f};

    // staging map: thread -> (row = tid>>1, k-half = (tid&1)*16)
    const int srow = tid >> 1;
    const int skh = (tid & 1) * 16;
    const float* pa = A + (bm + srow) * 768 + skh;
    const float* pb = B + (bn + srow) * 768 + skh;
    const int c0 = skh >> 3;                       // chunk 0 or 2
    const int wo0 = srow * 32 + ((c0 ^ (srow & 3)) * 8);
    const int wo1 = srow * 32 + (((c0 + 1) ^ (srow & 3)) * 8);
    // frag read swizzle: (lrow&3) == (lane&3) for all sub-tiles
    const int csw = (((lane >> 4) ^ (lane & 3)) * 8);

    for (int k0 = 0; k0 < 768; k0 += 32) {
        float4 a0 = *(const float4*)(pa + k0);
        float4 a1 = *(const float4*)(pa + k0 + 4);
        float4 a2 = *(const float4*)(pa + k0 + 8);
        float4 a3 = *(const float4*)(pa + k0 + 12);
        float4 b0 = *(const float4*)(pb + k0);
        float4 b1 = *(const float4*)(pb + k0 + 4);
        float4 b2 = *(const float4*)(pb + k0 + 8);
        float4 b3 = *(const float4*)(pb + k0 + 12);
        __syncthreads();       // prior iteration's LDS reads done
        {
            float av[16] = {a0.x, a0.y, a0.z, a0.w, a1.x, a1.y, a1.z, a1.w,
                            a2.x, a2.y, a2.z, a2.w, a3.x, a3.y, a3.z, a3.w};
            float bv[16] = {b0.x, b0.y, b0.z, b0.w, b1.x, b1.y, b1.z, b1.w,
                            b2.x, b2.y, b2.z, b2.w, b3.x, b3.y, b3.z, b3.w};
            f16x8 h, m;
#pragma unroll
            for (int j = 0; j < 8; ++j) {
                f16 hh = (f16)av[j]; h[j] = hh; m[j] = (f16)(av[j] - (float)hh);
            }
            *(f16x8*)&Ah[wo0] = h; *(f16x8*)&Am[wo0] = m;
#pragma unroll
            for (int j = 0; j < 8; ++j) {
                f16 hh = (f16)av[j + 8]; h[j] = hh; m[j] = (f16)(av[j + 8] - (float)hh);
            }
            *(f16x8*)&Ah[wo1] = h; *(f16x8*)&Am[wo1] = m;
#pragma unroll
            for (int j = 0; j < 8; ++j) {
                f16 hh = (f16)bv[j]; h[j] = hh; m[j] = (f16)(bv[j] - (float)hh);
            }
            *(f16x8*)&Bh[wo0] = h; *(f16x8*)&Bm[wo0] = m;
#pragma unroll
            for (int j = 0; j < 8; ++j) {
                f16 hh = (f16)bv[j + 8]; h[j] = hh; m[j] = (f16)(bv[j + 8] - (float)hh);
            }
            *(f16x8*)&Bh[wo1] = h; *(f16x8*)&Bm[wo1] = m;
        }
        __syncthreads();

        f16x8 fah[4], fam[4], fbh[4], fbm[4];
#pragma unroll
        for (int mi = 0; mi < 4; ++mi) {
            int off = (wr * 64 + mi * 16 + (lane & 15)) * 32 + csw;
            fah[mi] = *(const f16x8*)&Ah[off];
            fam[mi] = *(const f16x8*)&Am[off];
        }
#pragma unroll
        for (int ni = 0; ni < 4; ++ni) {
            int off = (wc * 64 + ni * 16 + (lane & 15)) * 32 + csw;
            fbh[ni] = *(const f16x8*)&Bh[off];
            fbm[ni] = *(const f16x8*)&Bm[off];
        }
#pragma unroll
        for (int mi = 0; mi < 4; ++mi)
#pragma unroll
            for (int ni = 0; ni < 4; ++ni) {
                acc[mi][ni] = __builtin_amdgcn_mfma_f32_16x16x32_f16(
                    fah[mi], fbh[ni], acc[mi][ni], 0, 0, 0);
                acc[mi][ni] = __builtin_amdgcn_mfma_f32_16x16x32_f16(
                    fah[mi], fbm[ni], acc[mi][ni], 0, 0, 0);
                acc[mi][ni] = __builtin_amdgcn_mfma_f32_16x16x32_f16(
                    fam[mi], fbh[ni], acc[mi][ni], 0, 0, 0);
            }
    }

    // epilogue: C/D layout col = lane&15, row = (lane>>4)*4 + reg
    const int orow0 = wr * 64 + (lane >> 4) * 4;
    const int ocol0 = wc * 64 + (lane & 15);
#pragma unroll
    for (int mi = 0; mi < 4; ++mi)
#pragma unroll
        for (int ni = 0; ni < 4; ++ni) {
            size_t col = bn + ocol0 + ni * 16;
            float badd = bias ? bscale * bias[col] : 0.f;
            size_t rbase = bm + orow0 + mi * 16;
#pragma unroll
            for (int r = 0; r < 4; ++r)
                C[(rbase + r) * N + col] = alpha * acc[mi][ni][r] + badd;
        }
}

// ---------------------------------------------------------------------------
// wave top-NR of a 2048-score row: (value desc, index asc) = jax.lax.top_k.
// All lanes of the wave end with identical topv/topi.
// ---------------------------------------------------------------------------
template <int NR>
__device__ void wave_topk(const float* __restrict__ srow, int lane,
                          float* topv, int* topi)
{
    float vals[32];
#pragma unroll
    for (int i = 0; i < 32; ++i) vals[i] = srow[lane + (i << 6)];
#pragma unroll
    for (int r = 0; r < NR; ++r) {
        float bvv = -3.4e38f; int bii = 0x7fffffff;
#pragma unroll
        for (int i = 0; i < 32; ++i)
            if (vals[i] > bvv) { bvv = vals[i]; bii = lane + (i << 6); }
#pragma unroll
        for (int off = 32; off > 0; off >>= 1) {
            float ov = __shfl_xor(bvv, off);
            int   oi = __shfl_xor(bii, off);
            if (ov > bvv || (ov == bvv && oi < bii)) { bvv = ov; bii = oi; }
        }
        topv[r] = bvv; topi[r] = bii;
        if ((bii & 63) == lane) vals[bii >> 6] = -3.4e38f;
    }
}

// ---------------------------------------------------------------------------
// select_combine: one wave per row. top-9; gap test; softmax top-8; combine.
// Ambiguous rows (gap < TAU) appended to list for exact f64 fixup.
// ---------------------------------------------------------------------------
__global__ __launch_bounds__(256) void select_combine(
    const float* __restrict__ scores,   // chunk base [tc][2048]
    const float* __restrict__ v,        // [2048][768]
    float* __restrict__ retrc,          // chunk base [tc][768]
    int* __restrict__ amb_count, int* __restrict__ amb_rows)
{
    const int lane = threadIdx.x & 63;
    const int wave = threadIdx.x >> 6;
    const int row = blockIdx.x * 4 + wave;

    float topv[9]; int topi[9];
    wave_topk<9>(scores + (size_t)row * S2, lane, topv, topi);

    if ((topv[7] - topv[8]) < TAU && lane == 0) {
        int idx = atomicAdd(amb_count, 1);
        if (idx < AMB_CAP) amb_rows[idx] = row;
    }

    float m = topv[0], w[KTOP], sum = 0.f;
#pragma unroll
    for (int r = 0; r < KTOP; ++r) { w[r] = expf(topv[r] - m); sum += w[r]; }
    float inv = 1.f / sum;

    const float4* v4 = (const float4*)v;
    float4* o4 = (float4*)(retrc + (size_t)row * DD);
#pragma unroll
    for (int c = 0; c < 3; ++c) {
        int col = c * 64 + lane;
        float4 accv = {0.f, 0.f, 0.f, 0.f};
#pragma unroll
        for (int r = 0; r < KTOP; ++r) {
            float4 vv = v4[(size_t)topi[r] * (DD / 4) + col];
            float wr = w[r] * inv;
            accv.x += wr * vv.x; accv.y += wr * vv.y;
            accv.z += wr * vv.z; accv.w += wr * vv.w;
        }
        o4[col] = accv;
    }
}

// ---------------------------------------------------------------------------
// fixup_a: per ambiguous row: q64 = f64(x_row @ Wq) + bq ; top-16 f32 cands.
// ---------------------------------------------------------------------------
__global__ __launch_bounds__(256) void fixup_a(
    const int* __restrict__ amb_count, const int* __restrict__ amb_rows,
    const float* __restrict__ xc, const float* __restrict__ Wq,
    const float* __restrict__ bq, const float* __restrict__ scores,
    double* __restrict__ q64amb, int* __restrict__ cand)
{
    int n = *amb_count; if (n > AMB_CAP) n = AMB_CAP;
    const int i = blockIdx.x;
    if (i >= n) return;
    const int tid = threadIdx.x;
    const int row = amb_rows[i];
    __shared__ float xs[768];
    for (int j = tid; j < 768; j += 256) xs[j] = xc[(size_t)row * 768 + j];
    __syncthreads();
    double a0 = (double)bq[tid], a1 = (double)bq[tid + 256], a2 = (double)bq[tid + 512];
    for (int kI = 0; kI < 768; ++kI) {
        double xv = (double)xs[kI];
        const float* wr = Wq + (size_t)kI * 768;
        a0 = fma(xv, (double)wr[tid], a0);
        a1 = fma(xv, (double)wr[tid + 256], a1);
        a2 = fma(xv, (double)wr[tid + 512], a2);
    }
    double* qo = q64amb + (size_t)i * 768;
    qo[tid] = a0; qo[tid + 256] = a1; qo[tid + 512] = a2;

    if (tid < 64) {
        float topv[16]; int topi[16];
        wave_topk<16>(scores + (size_t)row * S2, tid, topv, topi);
        if (tid < 16) cand[i * 16 + tid] = topi[tid];
    }
}

// ---------------------------------------------------------------------------
// fixup_b: per (amb row, candidate): exact f64 score = q64 . (slot@Wk + bk)/sqrt(D)
// slot rebuilt in f64 (np-matching pooling).
// ---------------------------------------------------------------------------
__global__ __launch_bounds__(256) void fixup_b(
    const int* __restrict__ amb_count,
    const float* __restrict__ xb, const float* __restrict__ pm,
    const float* __restrict__ Wk, const float* __restrict__ bk,
    const double* __restrict__ q64amb, const int* __restrict__ cand,
    double* __restrict__ s64)
{
    int n = *amb_count; if (n > AMB_CAP) n = AMB_CAP;
    const int tid = threadIdx.x;
    __shared__ double slotd[768];
    __shared__ double red[256];
    for (int p = blockIdx.x; p < n * 16; p += gridDim.x) {
        const int i = p >> 4;
        const int s = cand[p];
        __syncthreads();
        for (int j = tid; j < 768; j += 256) {
            double sv;
            if (s < SS) {
                const float* xr = xb + (size_t)(4 * s) * 768 + j;
                sv = 0.25 * ((double)xr[0] + (double)xr[768] +
                             (double)xr[1536] + (double)xr[2304]);
            } else {
                sv = (double)pm[(size_t)(s - SS) * 768 + j];
            }
            slotd[j] = sv;
        }
        __syncthreads();
        double part = 0.0;
#pragma unroll
        for (int jj = 0; jj < 3; ++jj) {
            const int j = tid + jj * 256;
            double kc = (double)bk[j];
            for (int kI = 0; kI < 768; ++kI)
                kc = fma(slotd[kI], (double)Wk[(size_t)kI * 768 + j], kc);
            part = fma(q64amb[(size_t)i * 768 + j], kc, part);
        }
        red[tid] = part;
        __syncthreads();
        for (int st = 128; st > 0; st >>= 1) {
            if (tid < st) red[tid] += red[tid + st];
            __syncthreads();
        }
        if (tid == 0) s64[p] = red[0] / sqrt((double)DD);
    }
}

// ---------------------------------------------------------------------------
// fixup_c: per amb row: f64 top-8 of 16 (val desc, slot asc), f64 softmax,
// combine v rows, overwrite retr row.
// ---------------------------------------------------------------------------
__global__ __launch_bounds__(256) void fixup_c(
    const int* __restrict__ amb_count, const int* __restrict__ amb_rows,
    const int* __restrict__ cand, const double* __restrict__ s64,
    const float* __restrict__ v, float* __restrict__ retrc)
{
    int n = *amb_count; if (n > AMB_CAP) n = AMB_CAP;
    const int i = blockIdx.x;
    if (i >= n) return;
    const int tid = threadIdx.x;
    __shared__ float wsm[KTOP];
    __shared__ int seli[KTOP];
    if (tid == 0) {
        double cs[16]; int ci[16];
        for (int c = 0; c < 16; ++c) { cs[c] = s64[i * 16 + c]; ci[c] = cand[i * 16 + c]; }
        unsigned used = 0;
        double sv[KTOP]; int sx[KTOP];
        for (int r = 0; r < KTOP; ++r) {
            int bi = -1;
            for (int c = 0; c < 16; ++c) {
                if (used & (1u << c)) continue;
                if (bi < 0 || cs[c] > cs[bi] ||
                    (cs[c] == cs[bi] && ci[c] < ci[bi])) bi = c;
            }
            used |= (1u << bi); sv[r] = cs[bi]; sx[r] = ci[bi];
        }
        double mx = sv[0], es[KTOP], ssum = 0.0;
        for (int r = 0; r < KTOP; ++r) { es[r] = exp(sv[r] - mx); ssum += es[r]; }
        for (int r = 0; r < KTOP; ++r) { wsm[r] = (float)(es[r] / ssum); seli[r] = sx[r]; }
    }
    __syncthreads();
    const int row = amb_rows[i];
    for (int j = tid; j < 768; j += 256) {
        float o = 0.f;
#pragma unroll
        for (int r = 0; r < KTOP; ++r) o += wsm[r] * v[(size_t)seli[r] * 768 + j];
        retrc[(size_t)row * 768 + j] = o;
    }
}

// ---------------------------------------------------------------------------
extern "C" void kernel_launch(void* const* d_in, const int* in_sizes, int n_in,
                              void* d_out, int out_size, void* d_ws, size_t ws_size,
                              hipStream_t stream)
{
    const float* x  = (const float*)d_in[0];
    const float* Wq = (const float*)d_in[1];
    const float* bq = (const float*)d_in[2];
    const float* Wk = (const float*)d_in[3];
    const float* bk = (const float*)d_in[4];
    const float* Wv = (const float*)d_in[5];
    const float* bv = (const float*)d_in[6];
    const float* Wp = (const float*)d_in[7];
    const float* bp = (const float*)d_in[8];
    const float* pm = (const float*)d_in[9];
    float* out = (float*)d_out;
    float* ws  = (float*)d_ws;

    const float inv_sqrt_d = (float)(1.0 / sqrt((double)DD));
    const size_t TD  = (size_t)TT * DD;
    const size_t SD2 = (size_t)S2 * DD;
    const size_t WSZ = (size_t)DD * DD;     // 589824

    float* p = ws;
    float* WqT = p; p += WSZ;
    float* WkT = p; p += WSZ;
    float* WvT = p; p += WSZ;
    float* WpT = p; p += WSZ;
    float* slots = p; p += SD2;
    float* q32 = p; p += TD;
    float* k32 = p; p += SD2;
    float* v32 = p; p += SD2;
    float* retr = p; p += TD;
    double* q64amb = (double*)p; p += (size_t)AMB_CAP * DD * 2;
    double* s64 = (double*)p; p += (size_t)AMB_CAP * 16 * 2;
    int* cand = (int*)p; p += (size_t)AMB_CAP * 16;
    int* ambc = (int*)p; p += 64;
    int* ambrows = (int*)p; p += AMB_CAP;
    float* scores = p;
    size_t used = (size_t)(p - ws);

    long tc = TT;
    while (tc > 512 && (used + (size_t)tc * S2) * 4 > ws_size) tc >>= 1;

    transpose768<<<dim3(24, 24), 256, 0, stream>>>(Wq, WqT);
    transpose768<<<dim3(24, 24), 256, 0, stream>>>(Wk, WkT);
    transpose768<<<dim3(24, 24), 256, 0, stream>>>(Wv, WvT);
    transpose768<<<dim3(24, 24), 256, 0, stream>>>(Wp, WpT);

    for (int b = 0; b < BB; ++b) {
        const float* xb = x + (size_t)b * TD;
        build_slots<<<(SS * DD) / 256, 256, 0, stream>>>(xb, pm, slots);
        mfma_nt_split<<<dim3(6, 32), 256, 0, stream>>>(
            xb, WqT, bq, q32, DD, 1.f, 1.f);
        mfma_nt_split<<<dim3(6, 16), 256, 0, stream>>>(
            slots, WkT, bk, k32, DD, 1.f, 1.f);
        mfma_nt_split<<<dim3(6, 16), 256, 0, stream>>>(
            slots, WvT, bv, v32, DD, 1.f, 1.f);

        for (long t0 = 0; t0 < TT; t0 += tc) {
            zero1<<<1, 1, 0, stream>>>(ambc);
            mfma_nt_split<<<dim3(16, tc / 128), 256, 0, stream>>>(
                q32 + (size_t)t0 * DD, k32, (const float*)nullptr, scores,
                S2, inv_sqrt_d, 0.f);
            select_combine<<<tc / 4, 256, 0, stream>>>(
                scores, v32, retr + (size_t)t0 * DD, ambc, ambrows);
            fixup_a<<<AMB_CAP, 256, 0, stream>>>(
                ambc, ambrows, xb + (size_t)t0 * DD, Wq, bq, scores,
                q64amb, cand);
            fixup_b<<<2048, 256, 0, stream>>>(
                ambc, xb, pm, Wk, bk, q64amb, cand, s64);
            fixup_c<<<AMB_CAP, 256, 0, stream>>>(
                ambc, ambrows, cand, s64, v32, retr + (size_t)t0 * DD);
        }

        mfma_nt_split<<<dim3(6, 32), 256, 0, stream>>>(
            retr, WpT, bp, out + (size_t)b * TD, DD, RWEIGHT, RWEIGHT);
    }
}